// Round 11
// baseline (216.785 us; speedup 1.0000x reference)
//
#include <hip/hip_runtime.h>
#include <math.h>

#define BATCH 16384
#define LBL   512
#define HID   768
#define TR    128

typedef unsigned long long u64;
typedef unsigned short ushort_t;
typedef __attribute__((ext_vector_type(8))) short short8;
typedef __attribute__((ext_vector_type(4))) float f32x4;

__device__ __forceinline__ ushort_t f2bf(float f){
  unsigned u = __builtin_bit_cast(unsigned, f);
  u += 0x7FFFu + ((u >> 16) & 1u);
  return (ushort_t)(u >> 16);
}
__device__ __forceinline__ float softplusf(float x){
  return fmaxf(x, 0.0f) + log1pf(expf(-fabsf(x)));
}
// convert 8 fp32 (two float4) -> short8 bf16
__device__ __forceinline__ short8 cvt8(float4 x0, float4 x1){
  short8 a;
  a[0]=(short)f2bf(x0.x); a[1]=(short)f2bf(x0.y); a[2]=(short)f2bf(x0.z); a[3]=(short)f2bf(x0.w);
  a[4]=(short)f2bf(x1.x); a[5]=(short)f2bf(x1.y); a[6]=(short)f2bf(x1.z); a[7]=(short)f2bf(x1.w);
  return a;
}

// ============ k1: M = W0a@Wt, Q = W0b@Wl (plain bf16 [128][768]), W1->bf16, KV, zero out ============
__global__ __launch_bounds__(256) void k1(
    const float* __restrict__ W0, const float* __restrict__ Wt, const float* __restrict__ Wl,
    const float* __restrict__ bt, const float* __restrict__ bl, const float* __restrict__ b0,
    const float* __restrict__ W1,
    ushort_t* __restrict__ Mbf, ushort_t* __restrict__ Qbf, ushort_t* __restrict__ W1B,
    float* __restrict__ KV, float* __restrict__ out){
  __shared__ float sw[TR];
  int bi = blockIdx.x, t = threadIdx.x;
  if (bi < 256){
    int i = bi & 127;
    int isQ = bi >> 7;
    const float* src = isQ ? Wl : Wt;
    ushort_t* dst = isQ ? Qbf : Mbf;
    if (t < TR) sw[t] = W0[(size_t)i*256 + isQ*128 + t];
    if (!isQ && t < 128) W1B[i*128 + t] = f2bf(W1[i*128 + t]);
    __syncthreads();
    int c = t;
    float a0 = 0.f, a1 = 0.f, a2 = 0.f;
    #pragma unroll 8
    for (int a = 0; a < 128; a++){
      float w = sw[a];
      const float* r = src + (size_t)a*HID;
      a0 = fmaf(w, r[c], a0);
      a1 = fmaf(w, r[c+256], a1);
      a2 = fmaf(w, r[c+512], a2);
    }
    dst[(size_t)i*HID + c]       = f2bf(a0);
    dst[(size_t)i*HID + c + 256] = f2bf(a1);
    dst[(size_t)i*HID + c + 512] = f2bf(a2);
  } else {
    if (t < TR){
      float s = b0[t];
      const float* r = W0 + (size_t)t*256;
      for (int a = 0; a < 128; a++) s = fmaf(r[a], bt[a], s);
      for (int a = 0; a < 128; a++) s = fmaf(r[128+a], bl[a], s);
      KV[t] = s;
    }
    if (t == 0) out[0] = 0.f;
  }
}

// ============ k2: G-GEMM barrier-free (0..15) | bitpack (16..527) ============
__global__ __launch_bounds__(256) void k2(
    const float* __restrict__ labe, const ushort_t* __restrict__ Qbf,
    const int* __restrict__ tgt,
    ushort_t* __restrict__ Gt, u64* __restrict__ bits, float* __restrict__ inv){
  __shared__ __align__(16) ushort_t GTs[128][40];
  int bi = blockIdx.x, tid = threadIdx.x;
  int lane = tid & 63, wave = tid >> 6;
  int m = lane & 15, q = lane >> 4;

  if (bi < 16){
    // ---- G = labe @ Q^T, 32 labels, direct fragment loads, no barriers in K-loop ----
    int l0 = bi * 32;
    const float* ar[2];
    ar[0] = labe + (size_t)(l0 + m)*HID + q*8;
    ar[1] = labe + (size_t)(l0 + 16 + m)*HID + q*8;
    const ushort_t* br[2];
    #pragma unroll
    for (int ct = 0; ct < 2; ct++)
      br[ct] = Qbf + (size_t)(wave*32 + ct*16 + m)*HID + q*8;

    f32x4 acc[2][2] = {{{0,0,0,0},{0,0,0,0}},{{0,0,0,0},{0,0,0,0}}};
    #pragma unroll 2
    for (int c = 0; c < 24; c++){
      short8 bfr[2];
      #pragma unroll
      for (int ct = 0; ct < 2; ct++)
        bfr[ct] = *(const short8*)(br[ct] + c*32);
      #pragma unroll
      for (int rt = 0; rt < 2; rt++){
        float4 x0 = *(const float4*)(ar[rt] + c*32);
        float4 x1 = *(const float4*)(ar[rt] + c*32 + 4);
        short8 a = cvt8(x0, x1);
        #pragma unroll
        for (int ct = 0; ct < 2; ct++)
          acc[rt][ct] = __builtin_amdgcn_mfma_f32_16x16x32_bf16(a, bfr[ct], acc[rt][ct], 0, 0, 0);
      }
    }
    // transpose epilogue via LDS -> coalesced Gt write
    #pragma unroll
    for (int rt = 0; rt < 2; rt++)
      #pragma unroll
      for (int ct = 0; ct < 2; ct++){
        int col = wave*32 + ct*16 + m;
        #pragma unroll
        for (int r = 0; r < 4; r++)
          GTs[col][rt*16 + q*4 + r] = f2bf(acc[rt][ct][r]);
      }
    __syncthreads();
    int gi = tid >> 1, half = tid & 1;
    ushort_t* dstp = Gt + (size_t)gi*LBL + l0 + half*16;
    *(short8*)(dstp)     = *(const short8*)&GTs[gi][half*16];
    *(short8*)(dstp + 8) = *(const short8*)&GTs[gi][half*16 + 8];
  } else {
    // ---- bitpack 32 target rows: wave handles 8 rows ----
    int b0r = (bi - 16)*32;
    #pragma unroll
    for (int rr = 0; rr < 8; rr++){
      int row = b0r + wave*8 + rr;
      const int* rp = tgt + (size_t)row*LBL;
      int v[8];
      #pragma unroll
      for (int c = 0; c < 8; c++) v[c] = rp[c*64 + lane];
      int cnt = 0;
      #pragma unroll
      for (int c = 0; c < 8; c++){
        u64 mm = __ballot(v[c] != 0);
        if (lane == 0){ bits[(size_t)row*8 + c] = mm; cnt += __popcll(mm); }
      }
      if (lane == 0) inv[row] = 1.0f / (float)(cnt < 1 ? 1 : cnt);
    }
  }
}

// ============ k3: barrier-free 64-row U-GEMM (32 pos + 32 perm neg) + V + h0 + h1 + score ============
// 512 blocks x 256 thr, 32 samples/block. LDS ~37.6 KB -> 4 blocks/CU.
__global__ __launch_bounds__(256) void k3(const float* __restrict__ T, const ushort_t* __restrict__ Mbf,
                                          const float* __restrict__ KV, const ushort_t* __restrict__ Gt,
                                          const u64* __restrict__ BITS_, const float* __restrict__ INV,
                                          const int* __restrict__ perm, const ushort_t* __restrict__ W1b,
                                          const float* __restrict__ b1, const float* __restrict__ W2,
                                          const float* __restrict__ b2, float* __restrict__ out){
  __shared__ __align__(16) u64 bitsS[32*10];        // 80B pitch
  __shared__ __align__(16) ushort_t h0s[64][136];   // 0-31 pos, 32-63 neg
  __shared__ float sred[4*4*16*17];
  __shared__ float invs[32];
  __shared__ int   permS[32];

  int tid = threadIdx.x;
  int lane = tid & 63, wave = tid >> 6;
  int m = lane & 15, q = lane >> 4;
  int r0 = blockIdx.x * 32;

  if (tid < 128){
    int row = tid >> 2, seg = tid & 3;
    const int4* src = (const int4*)((const char*)BITS_ + (size_t)(r0+row)*64 + seg*16);
    *(int4*)((char*)bitsS + row*80 + seg*16) = *src;
  } else if (tid < 160){
    invs[tid & 31] = INV[r0 + (tid & 31)];
  } else if (tid < 192){
    permS[tid & 31] = perm[r0 + (tid & 31)];
  }
  __syncthreads();

  // ---- U-GEMM, direct fragment loads, zero barriers across K=768 ----
  // rows: rt0 = r0+m, rt1 = r0+16+m (pos); rt2/rt3 = perm-gathered neg rows
  const float* ar[4];
  ar[0] = T + (size_t)(r0 + m)*HID + q*8;
  ar[1] = T + (size_t)(r0 + 16 + m)*HID + q*8;
  ar[2] = T + (size_t)permS[m]*HID + q*8;
  ar[3] = T + (size_t)permS[16 + m]*HID + q*8;
  const ushort_t* br[2];
  #pragma unroll
  for (int ct = 0; ct < 2; ct++)
    br[ct] = Mbf + (size_t)(wave*32 + ct*16 + m)*HID + q*8;

  f32x4 acc[4][2];
  #pragma unroll
  for (int rt = 0; rt < 4; rt++)
    #pragma unroll
    for (int ct = 0; ct < 2; ct++)
      acc[rt][ct] = (f32x4){0.f,0.f,0.f,0.f};

  #pragma unroll 2
  for (int c = 0; c < 24; c++){
    short8 bfr[2];
    #pragma unroll
    for (int ct = 0; ct < 2; ct++)
      bfr[ct] = *(const short8*)(br[ct] + c*32);
    #pragma unroll
    for (int rt = 0; rt < 4; rt++){
      float4 x0 = *(const float4*)(ar[rt] + c*32);
      float4 x1 = *(const float4*)(ar[rt] + c*32 + 4);
      short8 a = cvt8(x0, x1);
      #pragma unroll
      for (int ct = 0; ct < 2; ct++)
        acc[rt][ct] = __builtin_amdgcn_mfma_f32_16x16x32_bf16(a, bfr[ct], acc[rt][ct], 0, 0, 0);
    }
  }

  // ---- V = mask @ G (K=512), Gt direct, prefetch 1-deep ----
  const unsigned char* bits_b = (const unsigned char*)bitsS;
  f32x4 accV[2][2] = {{{0,0,0,0},{0,0,0,0}},{{0,0,0,0},{0,0,0,0}}};
  const ushort_t* gp[2];
  #pragma unroll
  for (int ct = 0; ct < 2; ct++)
    gp[ct] = Gt + (size_t)(wave*32 + ct*16 + m)*LBL + q*8;
  short8 bcur[2], bnext[2];
  #pragma unroll
  for (int ct = 0; ct < 2; ct++) bcur[ct] = *(const short8*)(gp[ct]);
  for (int c = 0; c < 16; c++){
    if (c < 15){
      #pragma unroll
      for (int ct = 0; ct < 2; ct++) bnext[ct] = *(const short8*)(gp[ct] + (c+1)*32);
    }
    #pragma unroll
    for (int rt = 0; rt < 2; rt++){
      unsigned bb = bits_b[(rt*16 + m)*80 + c*4 + q];
      short8 a;
      #pragma unroll
      for (int j = 0; j < 8; j++) a[j] = (short)(((bb >> j) & 1u) ? 0x3F80 : 0);
      #pragma unroll
      for (int ct = 0; ct < 2; ct++)
        accV[rt][ct] = __builtin_amdgcn_mfma_f32_16x16x32_bf16(a, bcur[ct], accV[rt][ct], 0, 0, 0);
    }
    #pragma unroll
    for (int ct = 0; ct < 2; ct++) bcur[ct] = bnext[ct];
  }

  // ---- h0 both branches -> LDS ----
  #pragma unroll
  for (int rt = 0; rt < 2; rt++)
    #pragma unroll
    for (int ct = 0; ct < 2; ct++){
      int col = wave*32 + ct*16 + m;
      float kv = KV[col];
      #pragma unroll
      for (int r = 0; r < 4; r++){
        int rowl = rt*16 + q*4 + r;
        float v = accV[rt][ct][r] * invs[rowl] + kv;
        h0s[rowl][col]      = f2bf(fmaxf(acc[rt][ct][r]   + v, 0.f));
        h0s[32 + rowl][col] = f2bf(fmaxf(acc[rt+2][ct][r] + v, 0.f));
      }
    }
  __syncthreads();

  float w2c[2], b1c[2];
  #pragma unroll
  for (int ct = 0; ct < 2; ct++){
    int col = wave*32 + ct*16 + m;
    w2c[ct] = W2[col];
    b1c[ct] = b1[col];
  }
  float b2v = b2[0];

  #pragma unroll
  for (int rt2 = 0; rt2 < 4; rt2++){
    f32x4 accH[2] = {{0,0,0,0},{0,0,0,0}};
    #pragma unroll
    for (int kc = 0; kc < 4; kc++){
      short8 a = *(const short8*)&h0s[rt2*16 + m][kc*32 + q*8];
      #pragma unroll
      for (int ct = 0; ct < 2; ct++){
        short8 b = *(const short8*)(W1b + (size_t)(wave*32 + ct*16 + m)*TR + kc*32 + q*8);
        accH[ct] = __builtin_amdgcn_mfma_f32_16x16x32_bf16(a, b, accH[ct], 0, 0, 0);
      }
    }
    #pragma unroll
    for (int r = 0; r < 4; r++){
      float sp = 0.f;
      #pragma unroll
      for (int ct = 0; ct < 2; ct++)
        sp = fmaf(w2c[ct], fmaxf(accH[ct][r] + b1c[ct], 0.f), sp);
      sred[((wave*4 + rt2)*16 + q*4 + r)*17 + m] = sp;
    }
  }
  __syncthreads();

  if (tid < 64){
    int rt2 = tid >> 4, row = tid & 15;
    float s = b2v;
    #pragma unroll
    for (int wx = 0; wx < 4; wx++)
      #pragma unroll
      for (int n = 0; n < 16; n++) s += sred[((wx*4 + rt2)*16 + row)*17 + n];
    float val = (rt2 < 2) ? softplusf(-s) : softplusf(s);   // rt2 0,1 = pos branch
    #pragma unroll
    for (int off = 32; off > 0; off >>= 1) val += __shfl_down(val, off);
    if (tid == 0) atomicAdd(out, val * (1.0f / (float)BATCH));
  }
}

extern "C" void kernel_launch(void* const* d_in, const int* in_sizes, int n_in,
                              void* d_out, int out_size, void* d_ws, size_t ws_size,
                              hipStream_t stream){
  const float* text = (const float*)d_in[0];
  const float* labe = (const float*)d_in[1];
  const int*   tgt  = (const int*)  d_in[2];
  const int*   perm = (const int*)  d_in[3];
  const float* Wt   = (const float*)d_in[4];
  const float* bt   = (const float*)d_in[5];
  const float* Wl   = (const float*)d_in[6];
  const float* bl   = (const float*)d_in[7];
  const float* W0   = (const float*)d_in[8];
  const float* b0   = (const float*)d_in[9];
  const float* W1   = (const float*)d_in[10];
  const float* b1   = (const float*)d_in[11];
  const float* W2   = (const float*)d_in[12];
  const float* b2   = (const float*)d_in[13];

  char* wsb = (char*)d_ws;
  size_t off = 0;
  auto alloc = [&](size_t bytes){
    size_t r = off;
    off += (bytes + 255) & ~(size_t)255;
    return r;
  };
  ushort_t* MBF = (ushort_t*)(wsb + alloc((size_t)TR*HID*2));
  ushort_t* QBF = (ushort_t*)(wsb + alloc((size_t)TR*HID*2));
  ushort_t* GT  = (ushort_t*)(wsb + alloc((size_t)TR*LBL*2));
  ushort_t* W1B = (ushort_t*)(wsb + alloc((size_t)TR*TR*2));
  float*    KV  = (float*)   (wsb + alloc((size_t)TR*4));
  u64*      BITS= (u64*)     (wsb + alloc((size_t)BATCH*8*8));
  float*    INV = (float*)   (wsb + alloc((size_t)BATCH*4));
  float*    out = (float*)d_out;
  (void)ws_size; (void)in_sizes; (void)n_in; (void)out_size;

  k1<<<257, 256, 0, stream>>>(W0, Wt, Wl, bt, bl, b0, W1, MBF, QBF, W1B, KV, out);
  k2<<<528, 256, 0, stream>>>(labe, QBF, tgt, GT, BITS, INV);
  k3<<<512, 256, 0, stream>>>(text, MBF, KV, GT, BITS, INV, perm, W1B, b1, W2, b2, out);
}